// Round 8
// baseline (313.608 us; speedup 1.0000x reference)
//
#include <hip/hip_runtime.h>
#include <hip/hip_bf16.h>

#define N_NODES 50000
#define N_EDGES 640000
#define HDIM 128
#define NGRAPH 64
#define NOUT 5
#define NB_SCAN 196  /* (50000+255)/256 */
#define POOL_CH 16   /* chunks per graph in k_pool */

typedef __attribute__((ext_vector_type(4))) short short4v;
typedef __attribute__((ext_vector_type(8))) short short8v;
typedef __attribute__((ext_vector_type(4))) float float4v;

__device__ inline float blo(unsigned u) { return __uint_as_float(u << 16); }
__device__ inline float bhi(unsigned u) { return __uint_as_float(u & 0xffff0000u); }
__device__ inline unsigned short f2b(float f) {
    __hip_bfloat16 h = __float2bfloat16(f);
    return *reinterpret_cast<unsigned short*>(&h);
}

__global__ void k_count(const int* __restrict__ dst, int* __restrict__ cnt) {
    int e = blockIdx.x * blockDim.x + threadIdx.x;
    if (e < N_EDGES) atomicAdd(&cnt[dst[e]], 1);
}

__global__ void k_scan1(const int* __restrict__ cnt, int* __restrict__ rs, int* __restrict__ ps) {
    __shared__ int sh[256];
    int t = threadIdx.x;
    int i = blockIdx.x * 256 + t;
    int v = (i < N_NODES) ? cnt[i] : 0;
    sh[t] = v;
    __syncthreads();
    for (int off = 1; off < 256; off <<= 1) {
        int x = sh[t];
        if (t >= off) x += sh[t - off];
        __syncthreads();
        sh[t] = x;
        __syncthreads();
    }
    if (i < N_NODES) rs[i] = sh[t] - v;
    if (t == 255) ps[blockIdx.x] = sh[255];
}

__global__ void k_scan2(int* __restrict__ ps) {
    __shared__ int sh[256];
    int t = threadIdx.x;
    int v = (t < NB_SCAN) ? ps[t] : 0;
    sh[t] = v;
    __syncthreads();
    for (int off = 1; off < 256; off <<= 1) {
        int x = sh[t];
        if (t >= off) x += sh[t - off];
        __syncthreads();
        sh[t] = x;
        __syncthreads();
    }
    if (t < NB_SCAN) ps[t] = sh[t] - v;
}

__global__ void k_scan3(const int* __restrict__ ps, int* __restrict__ rs, int* __restrict__ cur) {
    int i = blockIdx.x * 256 + threadIdx.x;
    if (i < N_NODES) {
        int v = rs[i] + ps[blockIdx.x];
        rs[i] = v;
        cur[i] = v;
    }
    if (i == 0) rs[N_NODES] = N_EDGES;
}

__global__ void k_scatter(const int* __restrict__ src, const int* __restrict__ dst,
                          int* __restrict__ cur, int* __restrict__ adj) {
    int e = blockIdx.x * blockDim.x + threadIdx.x;
    if (e < N_EDGES) {
        int d = dst[e];
        int pos = atomicAdd(&cur[d], 1);
        adj[pos] = src[e];
    }
}

// Fused prep: zero cur+pooled | gather 4 W matrices into MFMA fragment order |
// convert x f32 -> bf16. All independent ranges, one launch.
// wf entry e = [m][c][ks][lane], 8 bf16 (16B): lane (r=lane&15, g=lane>>4):
// frag = { W[k0+j][c*16+r] j=0..3, W[k0+16+j][c*16+r] j=0..3 }, k0 = ks*32+4g.
__global__ __launch_bounds__(256) void k_prep(const float* __restrict__ x,
                                              const float* __restrict__ w0a,
                                              const float* __restrict__ w0b,
                                              const float* __restrict__ w1a,
                                              const float* __restrict__ w1b,
                                              int* __restrict__ zero_p, int nz,
                                              unsigned short* __restrict__ wf,
                                              unsigned short* __restrict__ xb) {
    int i = blockIdx.x * 256 + threadIdx.x;
    if (i < nz) zero_p[i] = 0;
    if (i < 4 * 2048) {
        int m = i >> 11, rem = i & 2047;
        int c = rem >> 8, ks = (rem >> 6) & 3, lane = rem & 63;
        int r = lane & 15, g = lane >> 4;
        int n = c * 16 + r, k0 = ks * 32 + 4 * g;
        const float* w = (m == 0) ? w0a : (m == 1) ? w0b : (m == 2) ? w1a : w1b;
        unsigned short v[8];
#pragma unroll
        for (int j = 0; j < 4; j++) {
            v[j]     = f2b(w[(k0 + j) * HDIM + n]);
            v[4 + j] = f2b(w[(k0 + 16 + j) * HDIM + n]);
        }
        uint4 o;
        o.x = v[0] | ((unsigned)v[1] << 16);
        o.y = v[2] | ((unsigned)v[3] << 16);
        o.z = v[4] | ((unsigned)v[5] << 16);
        o.w = v[6] | ((unsigned)v[7] << 16);
        ((uint4*)wf)[i] = o;
    }
    if (i < N_NODES * HDIM / 8) {
        const float4* p = (const float4*)&x[(size_t)i * 8];
        float4 a = p[0], b = p[1];
        uint4 o;
        o.x = f2b(a.x) | ((unsigned)f2b(a.y) << 16);
        o.y = f2b(a.z) | ((unsigned)f2b(a.w) << 16);
        o.z = f2b(b.x) | ((unsigned)f2b(b.y) << 16);
        o.w = f2b(b.z) | ((unsigned)f2b(b.w) << 16);
        *(uint4*)&xb[(size_t)i * 8] = o;
    }
}

// Fused GIN layer: C = relu( relu( (A_i + sum_nbr A_j) @ W1 + b1 ) @ W2 + b2 ).
// The neighbor gather accumulates DIRECTLY in MFMA B-fragment layout:
// lane (r=lane&15, g=lane>>4) serves rows row0(+16), fragment elems per ks are
// {ks*32+4g+j, ks*32+16+4g+j} -> two uint2 (8B) loads per ks per neighbor,
// 4-lane group covers 32B contiguous per instr (sector-aligned). The aggregated
// row never touches memory; bf16 rounding points identical to the split
// agg->mlp version (same CSR order) so numerics are bitwise unchanged.
// Weights staged to LDS AFTER the gather (no vmcnt stall before gather starts),
// one barrier, then both matmuls register-resident as in R6/R7.
__global__ __launch_bounds__(256, 2) void k_gin(const unsigned short* __restrict__ A,
                                                const int* __restrict__ rs,
                                                const int* __restrict__ adj,
                                                const unsigned short* __restrict__ w1f,
                                                const unsigned short* __restrict__ w2f,
                                                const float* __restrict__ b1,
                                                const float* __restrict__ b2,
                                                unsigned short* __restrict__ C) {
    __shared__ uint4 lw1[2048];
    __shared__ uint4 lw2[2048];
    int tid = threadIdx.x;
    int lane = tid & 63;
    int w = tid >> 6;
    int r = lane & 15;
    int g = lane >> 4;
    int row0 = blockIdx.x * 128 + w * 32 + r;  // rt adds 16

    // ---- gather + GIN aggregation, directly into B-fragments ----
    short8v fbv[2][4];
#pragma unroll
    for (int rt = 0; rt < 2; rt++) {
        int row = row0 + rt * 16;
        bool ok = (row < N_NODES);
        int rowc = ok ? row : (N_NODES - 1);
        const unsigned short* arow = A + (size_t)rowc * HDIM;
        float acc[4][8];  // [ks][half*4+j]
#pragma unroll
        for (int ks = 0; ks < 4; ks++) {
            int k0 = ks * 32 + 4 * g;
            uint2 lo = *(const uint2*)(arow + k0);
            uint2 hi = *(const uint2*)(arow + k0 + 16);
            acc[ks][0] = blo(lo.x); acc[ks][1] = bhi(lo.x);
            acc[ks][2] = blo(lo.y); acc[ks][3] = bhi(lo.y);
            acc[ks][4] = blo(hi.x); acc[ks][5] = bhi(hi.x);
            acc[ks][6] = blo(hi.y); acc[ks][7] = bhi(hi.y);
        }
        int s = ok ? rs[row] : 0;
        int e = ok ? rs[row + 1] : 0;
        for (int k = s; k < e; k++) {
            int j = adj[k];
            const unsigned short* p = A + (size_t)j * HDIM;
#pragma unroll
            for (int ks = 0; ks < 4; ks++) {
                int k0 = ks * 32 + 4 * g;
                uint2 lo = *(const uint2*)(p + k0);
                uint2 hi = *(const uint2*)(p + k0 + 16);
                acc[ks][0] += blo(lo.x); acc[ks][1] += bhi(lo.x);
                acc[ks][2] += blo(lo.y); acc[ks][3] += bhi(lo.y);
                acc[ks][4] += blo(hi.x); acc[ks][5] += bhi(hi.x);
                acc[ks][6] += blo(hi.y); acc[ks][7] += bhi(hi.y);
            }
        }
#pragma unroll
        for (int ks = 0; ks < 4; ks++) {
            short8v f;
#pragma unroll
            for (int j2 = 0; j2 < 8; j2++) f[j2] = (short)f2b(acc[ks][j2]);
            fbv[rt][ks] = f;
        }
    }

    // ---- stage W1/W2 into LDS (linear 16B/lane, conflict-free) ----
    {
        const uint4* g1 = (const uint4*)w1f;
        const uint4* g2 = (const uint4*)w2f;
#pragma unroll
        for (int i = 0; i < 8; i++) lw1[tid + i * 256] = g1[tid + i * 256];
#pragma unroll
        for (int i = 0; i < 8; i++) lw2[tid + i * 256] = g2[tid + i * 256];
    }
    __syncthreads();

    // ---- mm1: z1 = agg @ W1 ----
    float4v acc1[2][8];
#pragma unroll
    for (int rt = 0; rt < 2; rt++)
#pragma unroll
        for (int c = 0; c < 8; c++) acc1[rt][c] = (float4v){0.f, 0.f, 0.f, 0.f};
#pragma unroll
    for (int ks = 0; ks < 4; ks++)
#pragma unroll
        for (int c = 0; c < 8; c++) {
            short8v fa = *(const short8v*)&lw1[(c * 4 + ks) * 64 + lane];
#pragma unroll
            for (int rt = 0; rt < 2; rt++)
                acc1[rt][c] = __builtin_amdgcn_mfma_f32_16x16x32_bf16(fa, fbv[rt][ks], acc1[rt][c], 0, 0, 0);
        }

    // ---- bias1 + inner ReLU + in-register repack into mm2 B-fragments ----
    short8v fb2[2][4];
#pragma unroll
    for (int ks = 0; ks < 4; ks++) {
        float4 bA = *(const float4*)&b1[(2 * ks) * 16 + 4 * g];
        float4 bB = *(const float4*)&b1[(2 * ks + 1) * 16 + 4 * g];
#pragma unroll
        for (int rt = 0; rt < 2; rt++) {
            short8v f;
            f[0] = (short)f2b(fmaxf(acc1[rt][2 * ks][0] + bA.x, 0.f));
            f[1] = (short)f2b(fmaxf(acc1[rt][2 * ks][1] + bA.y, 0.f));
            f[2] = (short)f2b(fmaxf(acc1[rt][2 * ks][2] + bA.z, 0.f));
            f[3] = (short)f2b(fmaxf(acc1[rt][2 * ks][3] + bA.w, 0.f));
            f[4] = (short)f2b(fmaxf(acc1[rt][2 * ks + 1][0] + bB.x, 0.f));
            f[5] = (short)f2b(fmaxf(acc1[rt][2 * ks + 1][1] + bB.y, 0.f));
            f[6] = (short)f2b(fmaxf(acc1[rt][2 * ks + 1][2] + bB.z, 0.f));
            f[7] = (short)f2b(fmaxf(acc1[rt][2 * ks + 1][3] + bB.w, 0.f));
            fb2[rt][ks] = f;
        }
    }

    // ---- mm2: z2 = z1 @ W2 ----
    float4v acc2[2][8];
#pragma unroll
    for (int rt = 0; rt < 2; rt++)
#pragma unroll
        for (int c = 0; c < 8; c++) acc2[rt][c] = (float4v){0.f, 0.f, 0.f, 0.f};
#pragma unroll
    for (int ks = 0; ks < 4; ks++)
#pragma unroll
        for (int c = 0; c < 8; c++) {
            short8v fa = *(const short8v*)&lw2[(c * 4 + ks) * 64 + lane];
#pragma unroll
            for (int rt = 0; rt < 2; rt++)
                acc2[rt][c] = __builtin_amdgcn_mfma_f32_16x16x32_bf16(fa, fb2[rt][ks], acc2[rt][c], 0, 0, 0);
        }

    // ---- bias2 + outer ReLU + store ----
#pragma unroll
    for (int rt = 0; rt < 2; rt++) {
        int row = row0 + rt * 16;
        bool ok = (row < N_NODES);
#pragma unroll
        for (int c = 0; c < 8; c++) {
            int colb = c * 16 + 4 * g;
            float4 bv = *(const float4*)&b2[colb];
            uint2 st;
            st.x = f2b(fmaxf(acc2[rt][c][0] + bv.x, 0.f)) |
                   ((unsigned)f2b(fmaxf(acc2[rt][c][1] + bv.y, 0.f)) << 16);
            st.y = f2b(fmaxf(acc2[rt][c][2] + bv.z, 0.f)) |
                   ((unsigned)f2b(fmaxf(acc2[rt][c][3] + bv.w, 0.f)) << 16);
            if (ok) *(uint2*)&C[(size_t)row * HDIM + colb] = st;
        }
    }
}

// Per-graph feature-wise max over bf16 h (post-ReLU >= 0): atomicMax on uint bits.
__global__ __launch_bounds__(256) void k_pool(const unsigned short* __restrict__ h,
                                              float* __restrict__ pooledf) {
    unsigned* pooled = (unsigned*)pooledf;
    int g = blockIdx.x / POOL_CH;
    int c = blockIdx.x % POOL_CH;
    int s = (g * N_NODES + NGRAPH - 1) / NGRAPH;
    int e = ((g + 1) * N_NODES + NGRAPH - 1) / NGRAPH;
    int len = e - s;
    int cs = s + (len * c) / POOL_CH;
    int ce = s + (len * (c + 1)) / POOL_CH;
    int t = threadIdx.x;
    int f8 = (t & 15) * 8;
    int rg = t >> 4;  // 16 row-groups
    float m[8] = {0.f, 0.f, 0.f, 0.f, 0.f, 0.f, 0.f, 0.f};
    for (int i = cs + rg; i < ce; i += 16) {
        uint4 v = *(const uint4*)&h[(size_t)i * HDIM + f8];
        m[0] = fmaxf(m[0], blo(v.x)); m[1] = fmaxf(m[1], bhi(v.x));
        m[2] = fmaxf(m[2], blo(v.y)); m[3] = fmaxf(m[3], bhi(v.y));
        m[4] = fmaxf(m[4], blo(v.z)); m[5] = fmaxf(m[5], bhi(v.z));
        m[6] = fmaxf(m[6], blo(v.w)); m[7] = fmaxf(m[7], bhi(v.w));
    }
    __shared__ float sh[16][HDIM];
#pragma unroll
    for (int j = 0; j < 8; j++) sh[rg][f8 + j] = m[j];
    __syncthreads();
    if (t < HDIM) {
        float mm = sh[0][t];
#pragma unroll
        for (int rr = 1; rr < 16; rr++) mm = fmaxf(mm, sh[rr][t]);
        atomicMax(&pooled[g * HDIM + t], __float_as_uint(mm));
    }
}

__global__ void k_final(const float* __restrict__ pooled, const float* __restrict__ lw,
                        const float* __restrict__ lb, float* __restrict__ out) {
    int t = threadIdx.x;  // 320 threads
    if (t >= NGRAPH * NOUT) return;
    int g = t / NOUT, o = t % NOUT;
    float acc = lb[o];
    for (int k = 0; k < HDIM; k++) acc = fmaf(pooled[g * HDIM + k], lw[k * NOUT + o], acc);
    out[t] = acc;
}

extern "C" void kernel_launch(void* const* d_in, const int* in_sizes, int n_in,
                              void* d_out, int out_size, void* d_ws, size_t ws_size,
                              hipStream_t stream) {
    const float* x    = (const float*)d_in[0];
    const int*   ei   = (const int*)d_in[1];
    const int*   srcv = ei;              // row 0
    const int*   dstv = ei + N_EDGES;    // row 1
    const float* c0w1 = (const float*)d_in[3];
    const float* c0b1 = (const float*)d_in[4];
    const float* c0w2 = (const float*)d_in[5];
    const float* c0b2 = (const float*)d_in[6];
    const float* c1w1 = (const float*)d_in[7];
    const float* c1b1 = (const float*)d_in[8];
    const float* c1w2 = (const float*)d_in[9];
    const float* c1b2 = (const float*)d_in[10];
    const float* lw   = (const float*)d_in[11];
    const float* lb   = (const float*)d_in[12];
    float* out = (float*)d_out;

    char* ws = (char*)d_ws;
    int* rs     = (int*)(ws);                          // N+1 ints
    int* cur    = (int*)(ws + 256 * 1024);             // N ints; pooled follows
    float* pooled = (float*)(cur + N_NODES);           // G*128 f32, zeroed with cur
    int* ps     = (int*)(ws + 512 * 1024);             // NB_SCAN ints
    int* adj    = (int*)(ws + 768 * 1024);             // E ints (2.56 MB)
    unsigned short* wf = (unsigned short*)(ws + 3584 * 1024);          // 4 x 32KB frag-order bf16
    unsigned short* xb = (unsigned short*)(ws + 4ull * 1024 * 1024);   // N*128 bf16 (12.8 MB)
    unsigned short* b1 = (unsigned short*)(ws + 17ull * 1024 * 1024);  // h1
    unsigned short* b2 = (unsigned short*)(ws + 30ull * 1024 * 1024);  // h2

    const int NZ  = N_NODES + NGRAPH * HDIM;           // cur + pooled
    const int NBE = (N_EDGES + 255) / 256;
    const int NBL = (N_NODES + 127) / 128;             // 391
    const int NBC = (N_NODES * HDIM / 8 + 255) / 256;  // 3125 (covers NZ and 8192 too)

    // ---- fused prep: zero cur+pooled | W->fragment order | x->bf16 ----
    k_prep<<<NBC, 256, 0, stream>>>(x, c0w1, c0w2, c1w1, c1w2, cur, NZ, wf, xb);

    // ---- CSR build ----
    k_count<<<NBE, 256, 0, stream>>>(dstv, cur);
    k_scan1<<<NB_SCAN, 256, 0, stream>>>(cur, rs, ps);
    k_scan2<<<1, 256, 0, stream>>>(ps);
    k_scan3<<<NB_SCAN, 256, 0, stream>>>(ps, rs, cur);
    k_scatter<<<NBE, 256, 0, stream>>>(srcv, dstv, cur, adj);

    // ---- layer 0: gather+MLP fused ----
    k_gin<<<NBL, 256, 0, stream>>>(xb, rs, adj, wf, wf + 16384, c0b1, c0b2, b1);

    // ---- layer 1 ----
    k_gin<<<NBL, 256, 0, stream>>>(b1, rs, adj, wf + 32768, wf + 49152, c1b1, c1b2, b2);

    // ---- readout ----
    k_pool<<<NGRAPH * POOL_CH, 256, 0, stream>>>(b2, pooled);
    k_final<<<1, 320, 0, stream>>>(pooled, lw, lb, out);
}

// Round 9
// 241.300 us; speedup vs baseline: 1.2997x; 1.2997x over previous
//
#include <hip/hip_runtime.h>
#include <hip/hip_bf16.h>

#define N_NODES 50000
#define N_EDGES 640000
#define HDIM 128
#define NGRAPH 64
#define NOUT 5
#define NB_SCAN 196  /* (50000+255)/256 */
#define POOL_CH 16   /* chunks per graph in k_pool */

typedef __attribute__((ext_vector_type(4))) short short4v;
typedef __attribute__((ext_vector_type(8))) short short8v;
typedef __attribute__((ext_vector_type(4))) float float4v;

__device__ inline float blo(unsigned u) { return __uint_as_float(u << 16); }
__device__ inline float bhi(unsigned u) { return __uint_as_float(u & 0xffff0000u); }
__device__ inline unsigned short f2b(float f) {
    __hip_bfloat16 h = __float2bfloat16(f);
    return *reinterpret_cast<unsigned short*>(&h);
}

// Node-feature rows are stored in FRAGMENT-PERMUTED order:
//   memory pos p = ks*32 + g*8 + h*4 + j  <->  logical col = ks*32 + h*16 + 4*g + j
// (ks,g in 0..3, h in 0..1, j in 0..3). agg/pool are column-permutation-
// transparent; mlp reads/writes 16B per (ks) directly in fragment layout;
// k_final un-permutes when indexing lw.

__global__ void k_count(const int* __restrict__ dst, int* __restrict__ cnt) {
    int e = blockIdx.x * blockDim.x + threadIdx.x;
    if (e < N_EDGES) atomicAdd(&cnt[dst[e]], 1);
}

__global__ void k_scan1(const int* __restrict__ cnt, int* __restrict__ rs, int* __restrict__ ps) {
    __shared__ int sh[256];
    int t = threadIdx.x;
    int i = blockIdx.x * 256 + t;
    int v = (i < N_NODES) ? cnt[i] : 0;
    sh[t] = v;
    __syncthreads();
    for (int off = 1; off < 256; off <<= 1) {
        int x = sh[t];
        if (t >= off) x += sh[t - off];
        __syncthreads();
        sh[t] = x;
        __syncthreads();
    }
    if (i < N_NODES) rs[i] = sh[t] - v;
    if (t == 255) ps[blockIdx.x] = sh[255];
}

__global__ void k_scan2(int* __restrict__ ps) {
    __shared__ int sh[256];
    int t = threadIdx.x;
    int v = (t < NB_SCAN) ? ps[t] : 0;
    sh[t] = v;
    __syncthreads();
    for (int off = 1; off < 256; off <<= 1) {
        int x = sh[t];
        if (t >= off) x += sh[t - off];
        __syncthreads();
        sh[t] = x;
        __syncthreads();
    }
    if (t < NB_SCAN) ps[t] = sh[t] - v;
}

__global__ void k_scan3(const int* __restrict__ ps, int* __restrict__ rs, int* __restrict__ cur) {
    int i = blockIdx.x * 256 + threadIdx.x;
    if (i < N_NODES) {
        int v = rs[i] + ps[blockIdx.x];
        rs[i] = v;
        cur[i] = v;
    }
    if (i == 0) rs[N_NODES] = N_EDGES;
}

__global__ void k_scatter(const int* __restrict__ src, const int* __restrict__ dst,
                          int* __restrict__ cur, int* __restrict__ adj) {
    int e = blockIdx.x * blockDim.x + threadIdx.x;
    if (e < N_EDGES) {
        int d = dst[e];
        int pos = atomicAdd(&cur[d], 1);
        adj[pos] = src[e];
    }
}

// Fused prep: zero cur+pooled | W -> MFMA fragment order | x f32 -> bf16
// in fragment-permuted row layout.
__global__ __launch_bounds__(256) void k_prep(const float* __restrict__ x,
                                              const float* __restrict__ w0a,
                                              const float* __restrict__ w0b,
                                              const float* __restrict__ w1a,
                                              const float* __restrict__ w1b,
                                              int* __restrict__ zero_p, int nz,
                                              unsigned short* __restrict__ wf,
                                              unsigned short* __restrict__ xb) {
    int i = blockIdx.x * 256 + threadIdx.x;
    if (i < nz) zero_p[i] = 0;
    if (i < 4 * 2048) {
        int m = i >> 11, rem = i & 2047;
        int c = rem >> 8, ks = (rem >> 6) & 3, lane = rem & 63;
        int r = lane & 15, g = lane >> 4;
        int n = c * 16 + r, k0 = ks * 32 + 4 * g;
        const float* w = (m == 0) ? w0a : (m == 1) ? w0b : (m == 2) ? w1a : w1b;
        unsigned short v[8];
#pragma unroll
        for (int j = 0; j < 4; j++) {
            v[j]     = f2b(w[(k0 + j) * HDIM + n]);
            v[4 + j] = f2b(w[(k0 + 16 + j) * HDIM + n]);
        }
        uint4 o;
        o.x = v[0] | ((unsigned)v[1] << 16);
        o.y = v[2] | ((unsigned)v[3] << 16);
        o.z = v[4] | ((unsigned)v[5] << 16);
        o.w = v[6] | ((unsigned)v[7] << 16);
        ((uint4*)wf)[i] = o;
    }
    if (i < N_NODES * 16) {
        int row = i >> 4;
        int p0 = (i & 15) * 8;                 // chunk position in permuted row
        int ks = p0 >> 5, g2 = (p0 >> 3) & 3;
        const float* xr = x + (size_t)row * HDIM + ks * 32 + 4 * g2;
        float4 a = *(const float4*)xr;         // h=0: cols +0..3
        float4 b = *(const float4*)(xr + 16);  // h=1: cols +16..19
        uint4 o;
        o.x = f2b(a.x) | ((unsigned)f2b(a.y) << 16);
        o.y = f2b(a.z) | ((unsigned)f2b(a.w) << 16);
        o.z = f2b(b.x) | ((unsigned)f2b(b.y) << 16);
        o.w = f2b(b.z) | ((unsigned)f2b(b.w) << 16);
        *(uint4*)&xb[(size_t)row * HDIM + p0] = o;
    }
}

// out[i] = h[i] + sum_{j in adj(i)} h[j]; bf16 rows (256B), 16 lanes x 16B per
// node. Neighbor loop software-pipelined 4-deep: 4 independent row loads in
// flight per lane-group (accumulation order per node preserved).
__global__ __launch_bounds__(256) void k_agg_b(const unsigned short* __restrict__ h,
                                               const int* __restrict__ rs,
                                               const int* __restrict__ adj,
                                               unsigned short* __restrict__ out) {
    int node = blockIdx.x * 16 + (threadIdx.x >> 4);
    if (node >= N_NODES) return;
    int c = (threadIdx.x & 15) * 8;  // ushort offset within row
    const unsigned short* hc = h + c;
    uint4 sv = *(const uint4*)(hc + (size_t)node * HDIM);
    float acc[8];
    acc[0] = blo(sv.x); acc[1] = bhi(sv.x);
    acc[2] = blo(sv.y); acc[3] = bhi(sv.y);
    acc[4] = blo(sv.z); acc[5] = bhi(sv.z);
    acc[6] = blo(sv.w); acc[7] = bhi(sv.w);
#define ACC8(v) do { \
        acc[0] += blo(v.x); acc[1] += bhi(v.x); \
        acc[2] += blo(v.y); acc[3] += bhi(v.y); \
        acc[4] += blo(v.z); acc[5] += bhi(v.z); \
        acc[6] += blo(v.w); acc[7] += bhi(v.w); } while (0)
    int s = rs[node], e = rs[node + 1];
    int k = s;
    for (; k + 4 <= e; k += 4) {
        int j0 = adj[k], j1 = adj[k + 1], j2 = adj[k + 2], j3 = adj[k + 3];
        uint4 v0 = *(const uint4*)(hc + (size_t)j0 * HDIM);
        uint4 v1 = *(const uint4*)(hc + (size_t)j1 * HDIM);
        uint4 v2 = *(const uint4*)(hc + (size_t)j2 * HDIM);
        uint4 v3 = *(const uint4*)(hc + (size_t)j3 * HDIM);
        ACC8(v0); ACC8(v1); ACC8(v2); ACC8(v3);
    }
    for (; k < e; k++) {
        int j = adj[k];
        uint4 v = *(const uint4*)(hc + (size_t)j * HDIM);
        ACC8(v);
    }
#undef ACC8
    uint4 o;
    o.x = f2b(acc[0]) | ((unsigned)f2b(acc[1]) << 16);
    o.y = f2b(acc[2]) | ((unsigned)f2b(acc[3]) << 16);
    o.z = f2b(acc[4]) | ((unsigned)f2b(acc[5]) << 16);
    o.w = f2b(acc[6]) | ((unsigned)f2b(acc[7]) << 16);
    *(uint4*)&out[(size_t)node * HDIM + c] = o;
}

// Fused GIN MLP: C = relu( relu(A@W1 + b1) @ W2 + b2 ), intermediate entirely
// in registers (mm1 D-regs ARE mm2 B-fragments per lane). Rows in fragment-
// permuted layout: A-read = one 16B load per ks; store = one 16B store per ks.
__global__ __launch_bounds__(256, 2) void k_mlp(const unsigned short* __restrict__ A,
                                                const unsigned short* __restrict__ w1f,
                                                const unsigned short* __restrict__ w2f,
                                                const float* __restrict__ b1,
                                                const float* __restrict__ b2,
                                                unsigned short* __restrict__ C) {
    __shared__ uint4 lw1[2048];
    __shared__ uint4 lw2[2048];
    int tid = threadIdx.x;
    int lane = tid & 63;
    int w = tid >> 6;
    int r = lane & 15;
    int g = lane >> 4;
    int row0 = blockIdx.x * 128 + w * 32 + r;  // rt adds 16

    // ---- A fragments: issue global loads FIRST (latency hides under staging) ----
    short8v fbv[2][4];
#pragma unroll
    for (int rt = 0; rt < 2; rt++) {
        int row = row0 + rt * 16;
        int rowc = (row < N_NODES) ? row : (N_NODES - 1);
        const unsigned short* arow = A + (size_t)rowc * HDIM;
#pragma unroll
        for (int ks = 0; ks < 4; ks++)
            fbv[rt][ks] = *(const short8v*)(arow + ks * 32 + g * 8);
    }

    // ---- stage W1/W2 into LDS (linear 16B/lane, conflict-free) ----
    {
        const uint4* g1 = (const uint4*)w1f;
        const uint4* g2 = (const uint4*)w2f;
#pragma unroll
        for (int i = 0; i < 8; i++) lw1[tid + i * 256] = g1[tid + i * 256];
#pragma unroll
        for (int i = 0; i < 8; i++) lw2[tid + i * 256] = g2[tid + i * 256];
    }
    __syncthreads();

    // ---- mm1: z1 = A @ W1 ----
    float4v acc1[2][8];
#pragma unroll
    for (int rt = 0; rt < 2; rt++)
#pragma unroll
        for (int c = 0; c < 8; c++) acc1[rt][c] = (float4v){0.f, 0.f, 0.f, 0.f};
#pragma unroll
    for (int ks = 0; ks < 4; ks++)
#pragma unroll
        for (int c = 0; c < 8; c++) {
            short8v fa = *(const short8v*)&lw1[(c * 4 + ks) * 64 + lane];
#pragma unroll
            for (int rt = 0; rt < 2; rt++)
                acc1[rt][c] = __builtin_amdgcn_mfma_f32_16x16x32_bf16(fa, fbv[rt][ks], acc1[rt][c], 0, 0, 0);
        }

    // ---- bias1 + inner ReLU + in-register repack into mm2 B-fragments ----
    short8v fb2[2][4];
#pragma unroll
    for (int ks = 0; ks < 4; ks++) {
        float4 bA = *(const float4*)&b1[(2 * ks) * 16 + 4 * g];
        float4 bB = *(const float4*)&b1[(2 * ks + 1) * 16 + 4 * g];
#pragma unroll
        for (int rt = 0; rt < 2; rt++) {
            short8v f;
            f[0] = (short)f2b(fmaxf(acc1[rt][2 * ks][0] + bA.x, 0.f));
            f[1] = (short)f2b(fmaxf(acc1[rt][2 * ks][1] + bA.y, 0.f));
            f[2] = (short)f2b(fmaxf(acc1[rt][2 * ks][2] + bA.z, 0.f));
            f[3] = (short)f2b(fmaxf(acc1[rt][2 * ks][3] + bA.w, 0.f));
            f[4] = (short)f2b(fmaxf(acc1[rt][2 * ks + 1][0] + bB.x, 0.f));
            f[5] = (short)f2b(fmaxf(acc1[rt][2 * ks + 1][1] + bB.y, 0.f));
            f[6] = (short)f2b(fmaxf(acc1[rt][2 * ks + 1][2] + bB.z, 0.f));
            f[7] = (short)f2b(fmaxf(acc1[rt][2 * ks + 1][3] + bB.w, 0.f));
            fb2[rt][ks] = f;
        }
    }

    // ---- mm2: z2 = z1 @ W2 ----
    float4v acc2[2][8];
#pragma unroll
    for (int rt = 0; rt < 2; rt++)
#pragma unroll
        for (int c = 0; c < 8; c++) acc2[rt][c] = (float4v){0.f, 0.f, 0.f, 0.f};
#pragma unroll
    for (int ks = 0; ks < 4; ks++)
#pragma unroll
        for (int c = 0; c < 8; c++) {
            short8v fa = *(const short8v*)&lw2[(c * 4 + ks) * 64 + lane];
#pragma unroll
            for (int rt = 0; rt < 2; rt++)
                acc2[rt][c] = __builtin_amdgcn_mfma_f32_16x16x32_bf16(fa, fb2[rt][ks], acc2[rt][c], 0, 0, 0);
        }

    // ---- bias2 + outer ReLU + store (fragment-permuted: 16B per ks) ----
#pragma unroll
    for (int rt = 0; rt < 2; rt++) {
        int row = row0 + rt * 16;
        bool ok = (row < N_NODES);
#pragma unroll
        for (int ks = 0; ks < 4; ks++) {
            float4 bA = *(const float4*)&b2[ks * 32 + 4 * g];
            float4 bB = *(const float4*)&b2[ks * 32 + 16 + 4 * g];
            uint4 st;
            st.x = f2b(fmaxf(acc2[rt][2 * ks][0] + bA.x, 0.f)) |
                   ((unsigned)f2b(fmaxf(acc2[rt][2 * ks][1] + bA.y, 0.f)) << 16);
            st.y = f2b(fmaxf(acc2[rt][2 * ks][2] + bA.z, 0.f)) |
                   ((unsigned)f2b(fmaxf(acc2[rt][2 * ks][3] + bA.w, 0.f)) << 16);
            st.z = f2b(fmaxf(acc2[rt][2 * ks + 1][0] + bB.x, 0.f)) |
                   ((unsigned)f2b(fmaxf(acc2[rt][2 * ks + 1][1] + bB.y, 0.f)) << 16);
            st.w = f2b(fmaxf(acc2[rt][2 * ks + 1][2] + bB.z, 0.f)) |
                   ((unsigned)f2b(fmaxf(acc2[rt][2 * ks + 1][3] + bB.w, 0.f)) << 16);
            if (ok) *(uint4*)&C[(size_t)row * HDIM + ks * 32 + g * 8] = st;
        }
    }
}

// Per-graph positional max over bf16 h (post-ReLU >= 0): atomicMax on uint bits.
// Positions are fragment-permuted; k_final un-permutes.
__global__ __launch_bounds__(256) void k_pool(const unsigned short* __restrict__ h,
                                              float* __restrict__ pooledf) {
    unsigned* pooled = (unsigned*)pooledf;
    int g = blockIdx.x / POOL_CH;
    int c = blockIdx.x % POOL_CH;
    int s = (g * N_NODES + NGRAPH - 1) / NGRAPH;
    int e = ((g + 1) * N_NODES + NGRAPH - 1) / NGRAPH;
    int len = e - s;
    int cs = s + (len * c) / POOL_CH;
    int ce = s + (len * (c + 1)) / POOL_CH;
    int t = threadIdx.x;
    int f8 = (t & 15) * 8;
    int rg = t >> 4;  // 16 row-groups
    float m[8] = {0.f, 0.f, 0.f, 0.f, 0.f, 0.f, 0.f, 0.f};
    for (int i = cs + rg; i < ce; i += 16) {
        uint4 v = *(const uint4*)&h[(size_t)i * HDIM + f8];
        m[0] = fmaxf(m[0], blo(v.x)); m[1] = fmaxf(m[1], bhi(v.x));
        m[2] = fmaxf(m[2], blo(v.y)); m[3] = fmaxf(m[3], bhi(v.y));
        m[4] = fmaxf(m[4], blo(v.z)); m[5] = fmaxf(m[5], bhi(v.z));
        m[6] = fmaxf(m[6], blo(v.w)); m[7] = fmaxf(m[7], bhi(v.w));
    }
    __shared__ float sh[16][HDIM];
#pragma unroll
    for (int j = 0; j < 8; j++) sh[rg][f8 + j] = m[j];
    __syncthreads();
    if (t < HDIM) {
        float mm = sh[0][t];
#pragma unroll
        for (int rr = 1; rr < 16; rr++) mm = fmaxf(mm, sh[rr][t]);
        atomicMax(&pooled[g * HDIM + t], __float_as_uint(mm));
    }
}

__global__ void k_final(const float* __restrict__ pooled, const float* __restrict__ lw,
                        const float* __restrict__ lb, float* __restrict__ out) {
    int t = threadIdx.x;  // 320 threads
    if (t >= NGRAPH * NOUT) return;
    int g = t / NOUT, o = t % NOUT;
    float acc = lb[o];
    for (int p = 0; p < HDIM; p++) {
        // pos p = ks*32+g2*8+h*4+j -> logical col = ks*32+h*16+4*g2+j
        int col = (p & 0x60) | ((p & 4) << 2) | ((p & 0x18) >> 1) | (p & 3);
        acc = fmaf(pooled[g * HDIM + p], lw[col * NOUT + o], acc);
    }
    out[t] = acc;
}

extern "C" void kernel_launch(void* const* d_in, const int* in_sizes, int n_in,
                              void* d_out, int out_size, void* d_ws, size_t ws_size,
                              hipStream_t stream) {
    const float* x    = (const float*)d_in[0];
    const int*   ei   = (const int*)d_in[1];
    const int*   srcv = ei;              // row 0
    const int*   dstv = ei + N_EDGES;    // row 1
    const float* c0w1 = (const float*)d_in[3];
    const float* c0b1 = (const float*)d_in[4];
    const float* c0w2 = (const float*)d_in[5];
    const float* c0b2 = (const float*)d_in[6];
    const float* c1w1 = (const float*)d_in[7];
    const float* c1b1 = (const float*)d_in[8];
    const float* c1w2 = (const float*)d_in[9];
    const float* c1b2 = (const float*)d_in[10];
    const float* lw   = (const float*)d_in[11];
    const float* lb   = (const float*)d_in[12];
    float* out = (float*)d_out;

    char* ws = (char*)d_ws;
    int* rs     = (int*)(ws);                          // N+1 ints
    int* cur    = (int*)(ws + 256 * 1024);             // N ints; pooled follows
    float* pooled = (float*)(cur + N_NODES);           // G*128 f32, zeroed with cur
    int* ps     = (int*)(ws + 512 * 1024);             // NB_SCAN ints
    int* adj    = (int*)(ws + 768 * 1024);             // E ints (2.56 MB)
    unsigned short* wf = (unsigned short*)(ws + 3584 * 1024);          // 4 x 32KB frag-order bf16
    unsigned short* xb = (unsigned short*)(ws + 4ull * 1024 * 1024);   // N*128 bf16 (12.8 MB)
    unsigned short* b0 = (unsigned short*)(ws + 17ull * 1024 * 1024);
    unsigned short* b1 = (unsigned short*)(ws + 30ull * 1024 * 1024);
    unsigned short* b2 = (unsigned short*)(ws + 43ull * 1024 * 1024);

    const int NZ  = N_NODES + NGRAPH * HDIM;           // cur + pooled
    const int NBE = (N_EDGES + 255) / 256;
    const int NBL = (N_NODES + 127) / 128;             // 391
    const int NBA = (N_NODES + 15) / 16;               // 3125
    const int NBC = (N_NODES * 16 + 255) / 256;        // 3125 (covers NZ and 8192 too)

    // ---- fused prep: zero cur+pooled | W->fragment order | x->bf16 permuted ----
    k_prep<<<NBC, 256, 0, stream>>>(x, c0w1, c0w2, c1w1, c1w2, cur, NZ, wf, xb);

    // ---- CSR build ----
    k_count<<<NBE, 256, 0, stream>>>(dstv, cur);
    k_scan1<<<NB_SCAN, 256, 0, stream>>>(cur, rs, ps);
    k_scan2<<<1, 256, 0, stream>>>(ps);
    k_scan3<<<NB_SCAN, 256, 0, stream>>>(ps, rs, cur);
    k_scatter<<<NBE, 256, 0, stream>>>(srcv, dstv, cur, adj);

    // ---- layer 0 ----
    k_agg_b<<<NBA, 256, 0, stream>>>(xb, rs, adj, b0);
    k_mlp<<<NBL, 256, 0, stream>>>(b0, wf, wf + 16384, c0b1, c0b2, b1);     // h1 -> b1

    // ---- layer 1 ----
    k_agg_b<<<NBA, 256, 0, stream>>>(b1, rs, adj, b0);
    k_mlp<<<NBL, 256, 0, stream>>>(b0, wf + 32768, wf + 49152, c1b1, c1b2, b2);  // h2 -> b2

    // ---- readout ----
    k_pool<<<NGRAPH * POOL_CH, 256, 0, stream>>>(b2, pooled);
    k_final<<<1, 320, 0, stream>>>(pooled, lw, lb, out);
}